// Round 12
// baseline (1367.793 us; speedup 1.0000x reference)
//
#include <hip/hip_runtime.h>

#define T_DIM 2048
#define B_DIM 32
#define D_DIM 128
#define H_DIM 512
#define L_DIM 6
#define C_DIM 10
#define BN_EPS 1e-5f

constexpr int TB = T_DIM * B_DIM;           // 65536 rows (t-major, then b)
constexpr size_t TBH = (size_t)TB * H_DIM;  // 33,554,432 floats = 128 MB

typedef short s16x8 __attribute__((ext_vector_type(8)));
typedef float f32x16 __attribute__((ext_vector_type(16)));

// ---- bf16 split helpers (bit-level, RNE) ----
__device__ inline unsigned short f2bf(float f) {
  unsigned u = __float_as_uint(f);
  unsigned r = (u + 0x7FFFu + ((u >> 16) & 1u)) >> 16;
  return (unsigned short)r;
}
__device__ inline float bf2f(unsigned short b) {
  return __uint_as_float((unsigned)b << 16);
}

// Workgroup barrier WITHOUT the vmcnt(0) drain that __syncthreads emits.
// Safe here because all cross-wave hazards at our barriers are LDS-only
// (destage ds_writes / ds_reads); global loads in flight (W ring, next-chunk
// A) carry only intra-wave deps, which the compiler orders with counted
// vmcnt (oldest-first semantics). This keeps the W-prefetch ring alive
// across chunk boundaries -- the structural ~20% stall of the 2-barrier
// K-loop (m97-class plateau).
__device__ inline void barrier_nodrain() {
  asm volatile("s_waitcnt lgkmcnt(0)" ::: "memory");
  __builtin_amdgcn_sched_barrier(0);
  __builtin_amdgcn_s_barrier();
}

// ---------------------------------------------------------------------------
// Split-bf16 MFMA GEMM, in-place safe (src may equal dst):
//   dst[m,o] = sum_k src[m,k] * W[o,k] + bias[o],  N = 512 fixed.
// R5 structure: 64 rows/block, 512 threads (8 waves), wave = 64 rows x 64
// cols (rf2 x cf2). A staged in K-chunks of 128 (double-buffered LDS, issue
// loads -> compute -> cvt+write), W read from global in pre-swizzled fragment
// order with ring-2 register prefetch. 3-MFMA split: Ah*Wh + Al*Wh + Ah*Wl.
// Barriers are lgkmcnt-only (see barrier_nodrain) so the W ring and
// next-chunk A loads stay in flight across chunk boundaries.
// W fragment layout: elem (o,k) at ((c32*NIT+itg)*64 + kg*32 + r31)*8 + j
//   where c32=o>>5, r31=o&31, itg=k>>4, kg=(k>>3)&1, j=k&7.
// Also zeroes stats[0..1023] from block 0 (safe: bn_fold, which reads stats,
// precedes this kernel in stream order; the scan that accumulates follows).
// ---------------------------------------------------------------------------
#define ROWS 64
#define BKC 128

template <int K>
__global__ __launch_bounds__(512, 4) void gemm_mfma(
    const float* src, const unsigned short* __restrict__ Whi,
    const unsigned short* __restrict__ Wlo, const float* __restrict__ bias,
    float* dst, float* stats) {
  constexpr int NC = K / BKC;     // 1 (K=128) or 4 (K=512)
  constexpr int NITC = BKC / 16;  // 8 MFMA k-steps per chunk
  constexpr int NIT = K / 16;
  __shared__ __align__(16) unsigned short AhS[2][ROWS * BKC];  // 32 KB
  __shared__ __align__(16) unsigned short AlS[2][ROWS * BKC];  // 32 KB

  const int tid = threadIdx.x;
  if (blockIdx.x == 0) {  // fold zero_stats into the GEMM
    stats[tid] = 0.f;
    stats[tid + 512] = 0.f;
  }
  const size_t row0 = (size_t)blockIdx.x * ROWS;
  const int lane = tid & 63;
  const int wave = tid >> 6;  // 0..7 = col-group of 64
  const int r31 = lane & 31;
  const int kg = lane >> 5;

  // staging: two 8-elem granules per thread per chunk (rows sr0, sr0+32)
  const int sr0 = tid >> 4, sk0 = tid & 15;
  const int sr1 = sr0 + 32;
  const size_t gidx0 = (row0 + sr0) * K + sk0 * 8;
  const size_t gidx1 = (row0 + sr1) * K + sk0 * 8;
  const int ss0 = sr0 * BKC + ((sk0 ^ (sr0 & 15)) << 3);
  const int ss1 = sr1 * BKC + ((sk0 ^ (sr1 & 15)) << 3);

  // W fragment bases for this wave's two col-frags (coalesced 16B/lane)
  const unsigned short* pWh0 =
      Whi + ((size_t)(wave * 2 + 0) * NIT * 64 + lane) * 8;
  const unsigned short* pWh1 =
      Whi + ((size_t)(wave * 2 + 1) * NIT * 64 + lane) * 8;
  const unsigned short* pWl0 =
      Wlo + ((size_t)(wave * 2 + 0) * NIT * 64 + lane) * 8;
  const unsigned short* pWl1 =
      Wlo + ((size_t)(wave * 2 + 1) * NIT * 64 + lane) * 8;

  auto cvt_store = [&](float4 a, float4 b, unsigned short* dh,
                       unsigned short* dl) {
    float vv[8] = {a.x, a.y, a.z, a.w, b.x, b.y, b.z, b.w};
    s16x8 hi, lo;
#pragma unroll
    for (int j = 0; j < 8; ++j) {
      unsigned short h = f2bf(vv[j]);
      hi[j] = (short)h;
      lo[j] = (short)f2bf(vv[j] - bf2f(h));
    }
    *(s16x8*)dh = hi;
    *(s16x8*)dl = lo;
  };

  // ---- prologue: stage chunk 0 ----
  {
    float4 a0 = *(const float4*)(src + gidx0);
    float4 a1 = *(const float4*)(src + gidx0 + 4);
    float4 b0 = *(const float4*)(src + gidx1);
    float4 b1 = *(const float4*)(src + gidx1 + 4);
    cvt_store(a0, a1, &AhS[0][ss0], &AlS[0][ss0]);
    cvt_store(b0, b1, &AhS[0][ss1], &AlS[0][ss1]);
  }
  // ---- W ring prologue: fragment itg=0 into slot 0 ----
  s16x8 whr[2][2], wlr[2][2];
  whr[0][0] = *(const s16x8*)pWh0;
  whr[0][1] = *(const s16x8*)pWh1;
  wlr[0][0] = *(const s16x8*)pWl0;
  wlr[0][1] = *(const s16x8*)pWl1;
  barrier_nodrain();

  f32x16 acc[2][2] = {};
  float4 a0, a1, b0, b1;  // in-flight next-chunk A
#pragma unroll
  for (int c = 0; c < NC; ++c) {
    if (c + 1 < NC) {  // issue next chunk's loads (hide under MFMAs)
      a0 = *(const float4*)(src + gidx0 + (c + 1) * BKC);
      a1 = *(const float4*)(src + gidx0 + (c + 1) * BKC + 4);
      b0 = *(const float4*)(src + gidx1 + (c + 1) * BKC);
      b1 = *(const float4*)(src + gidx1 + (c + 1) * BKC + 4);
    }
    const int bsel = c & 1;
#pragma unroll
    for (int it = 0; it < NITC; ++it) {
      const int itg = c * NITC + it;
      const int sl = it & 1, sn = (it + 1) & 1;
      if (itg + 1 < NIT) {  // ring-2 W prefetch
        whr[sn][0] = *(const s16x8*)(pWh0 + (size_t)(itg + 1) * 512);
        whr[sn][1] = *(const s16x8*)(pWh1 + (size_t)(itg + 1) * 512);
        wlr[sn][0] = *(const s16x8*)(pWl0 + (size_t)(itg + 1) * 512);
        wlr[sn][1] = *(const s16x8*)(pWl1 + (size_t)(itg + 1) * 512);
      }
      const int gi = it * 2 + kg;
      s16x8 ah[2], al[2];
#pragma unroll
      for (int rf = 0; rf < 2; ++rf) {
        const int row = rf * 32 + r31;
        const int aidx = row * BKC + ((gi ^ (row & 15)) << 3);
        ah[rf] = *(const s16x8*)&AhS[bsel][aidx];
        al[rf] = *(const s16x8*)&AlS[bsel][aidx];
      }
      // term-major: 4 independent MFMAs between touches of the same acc
#pragma unroll
      for (int cf = 0; cf < 2; ++cf)
#pragma unroll
        for (int rf = 0; rf < 2; ++rf)
          acc[rf][cf] = __builtin_amdgcn_mfma_f32_32x32x16_bf16(
              ah[rf], whr[sl][cf], acc[rf][cf], 0, 0, 0);
#pragma unroll
      for (int cf = 0; cf < 2; ++cf)
#pragma unroll
        for (int rf = 0; rf < 2; ++rf)
          acc[rf][cf] = __builtin_amdgcn_mfma_f32_32x32x16_bf16(
              al[rf], whr[sl][cf], acc[rf][cf], 0, 0, 0);
#pragma unroll
      for (int cf = 0; cf < 2; ++cf)
#pragma unroll
        for (int rf = 0; rf < 2; ++rf)
          acc[rf][cf] = __builtin_amdgcn_mfma_f32_32x32x16_bf16(
              ah[rf], wlr[sl][cf], acc[rf][cf], 0, 0, 0);
    }
    if (c + 1 < NC) {  // convert + write staged chunk, one barrier per chunk
      const int nb = (c + 1) & 1;
      cvt_store(a0, a1, &AhS[nb][ss0], &AlS[nb][ss0]);
      cvt_store(b0, b1, &AhS[nb][ss1], &AlS[nb][ss1]);
      barrier_nodrain();
    }
  }

  // ---- epilogue: D layout col=lane&31, row=(r&3)+8*(r>>2)+4*kg ----
#pragma unroll
  for (int cf = 0; cf < 2; ++cf) {
    const int o = wave * 64 + cf * 32 + r31;
    const float bb = bias[o];
#pragma unroll
    for (int rf = 0; rf < 2; ++rf) {
#pragma unroll
      for (int r = 0; r < 16; ++r) {
        int m = rf * 32 + (r & 3) + 8 * (r >> 2) + 4 * kg;
        dst[(row0 + m) * H_DIM + o] = acc[rf][cf][r] + bb;
      }
    }
  }
}

// ---------------------------------------------------------------------------
// IndRNN scan, in-place (z -> s, f32), accumulating per-channel sum/sumsq.
// One thread per (b,h) chain; CH=32 chunks, register double-buffered
// (load chunk n+1 while computing chunk n). 64-thread blocks -> 1 wave/CU.
// ---------------------------------------------------------------------------
__global__ __launch_bounds__(64) void indrnn_scan(float* __restrict__ z,
                                                  const float* __restrict__ u,
                                                  float* __restrict__ stats) {
  const int gid = blockIdx.x * 64 + threadIdx.x;  // 0..16383
  const int h = gid & (H_DIM - 1);
  const float uu = u[h];
  float hh = 0.f, sum = 0.f, sumsq = 0.f;
  float* p = z + gid;
  constexpr int STRIDE = B_DIM * H_DIM;  // 16384
  constexpr int CH = 32;
  constexpr int NCH = T_DIM / CH;  // 64 chunks
  float va[CH], vb[CH];

#define LOADC(dst, base)                                           \
  _Pragma("unroll") for (int c = 0; c < CH; ++c) dst[c] =          \
      p[(size_t)((base) + c) * STRIDE];
#define COMPC(dst)                                 \
  _Pragma("unroll") for (int c = 0; c < CH; ++c) { \
    hh = fmaxf(dst[c] + uu * hh, 0.f);             \
    dst[c] = hh;                                   \
    sum += hh;                                     \
    sumsq += hh * hh;                              \
  }
#define STOREC(dst, base)                          \
  _Pragma("unroll") for (int c = 0; c < CH; ++c)   \
      p[(size_t)((base) + c) * STRIDE] = dst[c];

  LOADC(va, 0)
  for (int i = 0; i < (NCH - 2) / 2; ++i) {
    const int t0 = i * 2 * CH;
    LOADC(vb, t0 + CH)
    COMPC(va)
    STOREC(va, t0)
    LOADC(va, t0 + 2 * CH)
    COMPC(vb)
    STOREC(vb, t0 + CH)
  }
  {
    const int t0 = (NCH - 2) * CH;
    LOADC(vb, t0 + CH)
    COMPC(va)
    STOREC(va, t0)
    COMPC(vb)
    STOREC(vb, t0 + CH)
  }
#undef LOADC
#undef COMPC
#undef STOREC
  atomicAdd(&stats[h], sum);
  atomicAdd(&stats[H_DIM + h], sumsq);
}

__global__ __launch_bounds__(64) void fill_sentinel(float* __restrict__ out,
                                                    int n) {
  for (int i = threadIdx.x; i < n; i += 64) out[i] = 1.0e6f;
}

// ---------------------------------------------------------------------------
// Convert raw f32 weights (layer 0) to bf16 hi/lo in fragment-swizzled order.
// ---------------------------------------------------------------------------
template <int K>
__global__ __launch_bounds__(256) void convert_w(
    const float* __restrict__ W, unsigned short* __restrict__ Whi,
    unsigned short* __restrict__ Wlo) {
  constexpr int NIT = K / 16;
  int i = blockIdx.x * 256 + threadIdx.x;
  if (i < H_DIM * K) {
    int o = i / K, k = i % K;
    float v = W[i];
    unsigned short h = f2bf(v);
    size_t idx =
        ((size_t)((o >> 5) * NIT + (k >> 4)) * 64 + ((k >> 3) & 1) * 32 +
         (o & 31)) * 8 + (k & 7);
    Whi[idx] = h;
    Wlo[idx] = f2bf(v - bf2f(h));
  }
}

// ---------------------------------------------------------------------------
// Fold BN of previous layer into next layer's weights, emit swizzled bf16:
//   a[i] = gamma[i]*rsqrt(var[i]+eps); c[i] = beta[i] - mean[i]*a[i]
//   Wf[o,i] = Wn[o,i]*a[i];  bf[o] = bn[o] + sum_i Wn[o,i]*c[i]
// ---------------------------------------------------------------------------
__global__ __launch_bounds__(256) void bn_fold(
    const float* __restrict__ stats, const float* __restrict__ gamma,
    const float* __restrict__ beta, const float* __restrict__ Wn,
    const float* __restrict__ bn, unsigned short* __restrict__ Whi,
    unsigned short* __restrict__ Wlo, float* __restrict__ bf) {
  constexpr int NIT = H_DIM / 16;
  const int o = blockIdx.x;
  const int tid = threadIdx.x;
  constexpr float invTB = 1.f / (float)(T_DIM * B_DIM);
  float part = 0.f;
  for (int i = tid; i < H_DIM; i += 256) {
    float mean = stats[i] * invTB;
    float var = stats[H_DIM + i] * invTB - mean * mean;
    float a = gamma[i] * rsqrtf(var + BN_EPS);
    float c = beta[i] - mean * a;
    float w = Wn[(size_t)o * H_DIM + i];
    float wf = w * a;
    unsigned short h = f2bf(wf);
    size_t idx =
        ((size_t)((o >> 5) * NIT + (i >> 4)) * 64 + ((i >> 3) & 1) * 32 +
         (o & 31)) * 8 + (i & 7);
    Whi[idx] = h;
    Wlo[idx] = f2bf(wf - bf2f(h));
    part += w * c;
  }
  __shared__ float red[256];
  red[tid] = part;
  __syncthreads();
  for (int s = 128; s > 0; s >>= 1) {
    if (tid < s) red[tid] += red[tid + s];
    __syncthreads();
  }
  if (tid == 0) bf[o] = bn[o] + red[0];
}

// ---------------------------------------------------------------------------
// Final: out[b,c] = sum_i (s5[T-1,b,i]*a5[i] + c5[i]) * Wout[c,i] + bout[c]
// ---------------------------------------------------------------------------
__global__ __launch_bounds__(64) void final_out(const float* __restrict__ s5,
                                                const float* __restrict__ stats,
                                                const float* __restrict__ gamma,
                                                const float* __restrict__ beta,
                                                const float* __restrict__ Wout,
                                                const float* __restrict__ bout,
                                                float* __restrict__ out) {
  const int b = blockIdx.x / C_DIM, cls = blockIdx.x % C_DIM;
  const int lane = threadIdx.x;
  constexpr float invTB = 1.f / (float)(T_DIM * B_DIM);
  const float* srow =
      s5 + (size_t)(T_DIM - 1) * B_DIM * H_DIM + (size_t)b * H_DIM;
  float part = 0.f;
  for (int i = lane; i < H_DIM; i += 64) {
    float mean = stats[i] * invTB;
    float var = stats[H_DIM + i] * invTB - mean * mean;
    float a = gamma[i] * rsqrtf(var + BN_EPS);
    float c = beta[i] - mean * a;
    part += (srow[i] * a + c) * Wout[(size_t)cls * H_DIM + i];
  }
#pragma unroll
  for (int off = 32; off > 0; off >>= 1) part += __shfl_down(part, off);
  if (lane == 0) out[b * C_DIM + cls] = part + bout[cls];
}

// ---------------------------------------------------------------------------
extern "C" void kernel_launch(void* const* d_in, const int* in_sizes, int n_in,
                              void* d_out, int out_size, void* d_ws,
                              size_t ws_size, hipStream_t stream) {
  const float* x     = (const float*)d_in[0];
  const float* W0    = (const float*)d_in[1];
  const float* b0    = (const float*)d_in[2];
  const float* Wh    = (const float*)d_in[3];
  const float* bh    = (const float*)d_in[4];
  const float* u     = (const float*)d_in[5];
  const float* gamma = (const float*)d_in[6];
  const float* beta  = (const float*)d_in[7];
  const float* Wout  = (const float*)d_in[8];
  const float* bout  = (const float*)d_in[9];
  float* out = (float*)d_out;

  const size_t need = TBH * sizeof(float) +
                      (size_t)H_DIM * H_DIM * 2 * sizeof(unsigned short) +
                      3 * H_DIM * sizeof(float);
  if (ws_size < need) {
    fill_sentinel<<<1, 64, 0, stream>>>(out, out_size);
    return;
  }

  float* ws = (float*)d_ws;
  float* buf = ws;                                     // 128 MB activations
  unsigned short* Whi = (unsigned short*)(ws + TBH);   // 512 KB
  unsigned short* Wlo = Whi + (size_t)H_DIM * H_DIM;   // 512 KB
  float* bf = (float*)(Wlo + (size_t)H_DIM * H_DIM);   // 2 KB
  float* stats = bf + H_DIM;                           // 4 KB

  const int gemm_blocks = TB / ROWS;  // 1024
  const int scan_blocks = (B_DIM * H_DIM) / 64;

  // ---- layer 0: x (f32, K=128) -> buf ----
  convert_w<D_DIM><<<(H_DIM * D_DIM + 255) / 256, 256, 0, stream>>>(W0, Whi,
                                                                    Wlo);
  gemm_mfma<D_DIM><<<gemm_blocks, 512, 0, stream>>>(x, Whi, Wlo, b0, buf,
                                                    stats);
  indrnn_scan<<<scan_blocks, 64, 0, stream>>>(buf, u, stats);

  // ---- layers 1..5: in-place buf -> buf ----
  for (int l = 1; l < L_DIM; ++l) {
    bn_fold<<<H_DIM, 256, 0, stream>>>(
        stats, gamma + (size_t)(l - 1) * H_DIM, beta + (size_t)(l - 1) * H_DIM,
        Wh + (size_t)(l - 1) * H_DIM * H_DIM, bh + (size_t)(l - 1) * H_DIM,
        Whi, Wlo, bf);
    gemm_mfma<H_DIM><<<gemm_blocks, 512, 0, stream>>>(buf, Whi, Wlo, bf, buf,
                                                      stats);
    indrnn_scan<<<scan_blocks, 64, 0, stream>>>(buf, u + (size_t)l * H_DIM,
                                                stats);
  }

  // ---- final projection (BN of layer 5 applied on the fly) ----
  final_out<<<B_DIM * C_DIM, 64, 0, stream>>>(
      buf, stats, gamma + 5 * (size_t)H_DIM, beta + 5 * (size_t)H_DIM, Wout,
      bout, out);
}

// Round 13
// 754.852 us; speedup vs baseline: 1.8120x; 1.8120x over previous
//
#include <hip/hip_runtime.h>

#define T_DIM 2048
#define B_DIM 32
#define D_DIM 128
#define H_DIM 512
#define L_DIM 6
#define C_DIM 10
#define BN_EPS 1e-5f

constexpr int TB = T_DIM * B_DIM;           // 65536 rows (t-major, then b)
constexpr size_t TBH = (size_t)TB * H_DIM;  // 33,554,432 elements
constexpr size_t PKN = TBH / 2;             // packed u32 count (64 MB)

typedef short s16x8 __attribute__((ext_vector_type(8)));
typedef float f32x16 __attribute__((ext_vector_type(16)));

// ---- bf16 helpers (bit-level, RNE) ----
__device__ inline unsigned short f2bf(float f) {
  unsigned u = __float_as_uint(f);
  unsigned r = (u + 0x7FFFu + ((u >> 16) & 1u)) >> 16;
  return (unsigned short)r;
}
__device__ inline float bf2f(unsigned short b) {
  return __uint_as_float((unsigned)b << 16);
}

// De-interleave 8 packed u32 (loT | hiT<<16) into two planar s16x8:
// dl0 = low halves (t-even row), dh1 = high halves (t-odd row).
__device__ inline void destage(uint4 q0, uint4 q1, unsigned short* dlo,
                               unsigned short* dhi) {
  uint4 lo, hi;
  lo.x = __builtin_amdgcn_perm(q0.y, q0.x, 0x05040100u);
  lo.y = __builtin_amdgcn_perm(q0.w, q0.z, 0x05040100u);
  lo.z = __builtin_amdgcn_perm(q1.y, q1.x, 0x05040100u);
  lo.w = __builtin_amdgcn_perm(q1.w, q1.z, 0x05040100u);
  hi.x = __builtin_amdgcn_perm(q0.y, q0.x, 0x07060302u);
  hi.y = __builtin_amdgcn_perm(q0.w, q0.z, 0x07060302u);
  hi.z = __builtin_amdgcn_perm(q1.y, q1.x, 0x07060302u);
  hi.w = __builtin_amdgcn_perm(q1.w, q1.z, 0x07060302u);
  *(uint4*)dlo = lo;
  *(uint4*)dhi = hi;
}

// ---------------------------------------------------------------------------
// bf16 MFMA GEMM over t-pair-packed activations, fully in-place:
//   z[t,b,o] = sum_k s[t,b,k] * W[o,k] + bias[o],  N = 512 fixed.
// Block i covers t in {2i, 2i+1}, all 32 b (64 rows); block-local row =
// b + 32*(t odd). Packed u32 index of (t,b,h) = (t/2)*16384 + b*512 + h, so
// block i reads AND writes exactly u32s [i*16384, (i+1)*16384) -- in-place
// safe with no cross-block overlap (epilogue writes after all A staged).
// 512 threads (8 waves), wave = 64 rows x 64 cols (rf2 x cf2). A staged in
// K-chunks of 128 (double-buffered 32 KB LDS), W (split hi/lo bf16) read
// from global in pre-swizzled fragment order with ring-2 register prefetch.
// A is exactly bf16 -> 2-term MFMA: Ah*Wh + Ah*Wl (vs 3-term f32-split).
// PACKED_IN=false (layer 0): reads f32 rows, rounds to bf16 (one term).
// W fragment layout: elem (o,k) at ((c32*NIT+itg)*64 + kg*32 + r31)*8 + j
//   where c32=o>>5, r31=o&31, itg=k>>4, kg=(k>>3)&1, j=k&7.
// Also zeroes stats[0..1023] from block 0 (safe: bn_fold, which reads stats,
// precedes this kernel in stream order; the scan that accumulates follows).
// ---------------------------------------------------------------------------
#define ROWS 64
#define BKC 128

template <int K, bool PACKED_IN>
__global__ __launch_bounds__(512, 4) void gemm_mfma(
    const void* src, const unsigned short* __restrict__ Whi,
    const unsigned short* __restrict__ Wlo, const float* __restrict__ bias,
    uint* __restrict__ dstP, float* stats) {
  constexpr int NC = K / BKC;     // 1 (K=128) or 4 (K=512)
  constexpr int NITC = BKC / 16;  // 8 MFMA k-steps per chunk
  constexpr int NIT = K / 16;
  __shared__ __align__(16) unsigned short AhS[2][ROWS * BKC];  // 2x16 KB

  const int tid = threadIdx.x;
  if (blockIdx.x == 0) {  // fold zero_stats into the GEMM
    stats[tid] = 0.f;
    stats[tid + 512] = 0.f;
  }
  const int lane = tid & 63;
  const int wave = tid >> 6;  // 0..7 = col-group of 64
  const int r31 = lane & 31;
  const int kg = lane >> 5;

  // staging: thread handles rows b=sr0 (t-even) and sr0+32 (t-odd),
  // granule sk0 (8 consecutive k).
  const int sr0 = tid >> 4, sk0 = tid & 15;
  const int ss0 = sr0 * BKC + ((sk0 ^ (sr0 & 15)) << 3);
  const int ss1 = (sr0 + 32) * BKC + ((sk0 ^ (sr0 & 15)) << 3);

  const size_t pbase = (size_t)blockIdx.x * 16384;  // block's u32 region
  const uint* srcP = (const uint*)src;
  const float* srcF = (const float*)src;
  const size_t row0 = (size_t)blockIdx.x * ROWS;  // f32 path row base

  // W fragment bases for this wave's two col-frags (coalesced 16B/lane)
  const unsigned short* pWh0 =
      Whi + ((size_t)(wave * 2 + 0) * NIT * 64 + lane) * 8;
  const unsigned short* pWh1 =
      Whi + ((size_t)(wave * 2 + 1) * NIT * 64 + lane) * 8;
  const unsigned short* pWl0 =
      Wlo + ((size_t)(wave * 2 + 0) * NIT * 64 + lane) * 8;
  const unsigned short* pWl1 =
      Wlo + ((size_t)(wave * 2 + 1) * NIT * 64 + lane) * 8;

  auto cvt8 = [&](float4 a, float4 b) {
    float vv[8] = {a.x, a.y, a.z, a.w, b.x, b.y, b.z, b.w};
    s16x8 hi;
#pragma unroll
    for (int j = 0; j < 8; ++j) hi[j] = (short)f2bf(vv[j]);
    return hi;
  };

  // ---- prologue: stage chunk 0 ----
  if (PACKED_IN) {
    uint4 q0 = *(const uint4*)(srcP + pbase + sr0 * 512 + sk0 * 8);
    uint4 q1 = *(const uint4*)(srcP + pbase + sr0 * 512 + sk0 * 8 + 4);
    destage(q0, q1, &AhS[0][ss0], &AhS[0][ss1]);
  } else {
    const size_t g0 = (row0 + sr0) * K + sk0 * 8;
    const size_t g1 = (row0 + sr0 + 32) * K + sk0 * 8;
    *(s16x8*)&AhS[0][ss0] =
        cvt8(*(const float4*)(srcF + g0), *(const float4*)(srcF + g0 + 4));
    *(s16x8*)&AhS[0][ss1] =
        cvt8(*(const float4*)(srcF + g1), *(const float4*)(srcF + g1 + 4));
  }
  // ---- W ring prologue: fragment itg=0 into slot 0 ----
  s16x8 whr[2][2], wlr[2][2];
  whr[0][0] = *(const s16x8*)pWh0;
  whr[0][1] = *(const s16x8*)pWh1;
  wlr[0][0] = *(const s16x8*)pWl0;
  wlr[0][1] = *(const s16x8*)pWl1;
  __syncthreads();

  f32x16 acc[2][2] = {};
  uint4 q0, q1;    // in-flight next-chunk A (packed)
  float4 f0, f1, f2, f3;  // in-flight next-chunk A (f32)
#pragma unroll
  for (int c = 0; c < NC; ++c) {
    if (c + 1 < NC) {  // issue next chunk's loads (hide under MFMAs)
      if (PACKED_IN) {
        q0 = *(const uint4*)(srcP + pbase + sr0 * 512 + (c + 1) * BKC +
                             sk0 * 8);
        q1 = *(const uint4*)(srcP + pbase + sr0 * 512 + (c + 1) * BKC +
                             sk0 * 8 + 4);
      } else {
        const size_t g0 = (row0 + sr0) * K + (c + 1) * BKC + sk0 * 8;
        const size_t g1 = (row0 + sr0 + 32) * K + (c + 1) * BKC + sk0 * 8;
        f0 = *(const float4*)(srcF + g0);
        f1 = *(const float4*)(srcF + g0 + 4);
        f2 = *(const float4*)(srcF + g1);
        f3 = *(const float4*)(srcF + g1 + 4);
      }
    }
    const int bsel = c & 1;
#pragma unroll
    for (int it = 0; it < NITC; ++it) {
      const int itg = c * NITC + it;
      const int sl = it & 1, sn = (it + 1) & 1;
      if (itg + 1 < NIT) {  // ring-2 W prefetch
        whr[sn][0] = *(const s16x8*)(pWh0 + (size_t)(itg + 1) * 512);
        whr[sn][1] = *(const s16x8*)(pWh1 + (size_t)(itg + 1) * 512);
        wlr[sn][0] = *(const s16x8*)(pWl0 + (size_t)(itg + 1) * 512);
        wlr[sn][1] = *(const s16x8*)(pWl1 + (size_t)(itg + 1) * 512);
      }
      const int gi = it * 2 + kg;
      s16x8 ah[2];
#pragma unroll
      for (int rf = 0; rf < 2; ++rf) {
        const int row = rf * 32 + r31;
        ah[rf] = *(const s16x8*)&AhS[bsel][row * BKC + ((gi ^ (row & 15)) << 3)];
      }
      // term-major: 4 independent MFMAs between touches of the same acc
#pragma unroll
      for (int cf = 0; cf < 2; ++cf)
#pragma unroll
        for (int rf = 0; rf < 2; ++rf)
          acc[rf][cf] = __builtin_amdgcn_mfma_f32_32x32x16_bf16(
              ah[rf], whr[sl][cf], acc[rf][cf], 0, 0, 0);
#pragma unroll
      for (int cf = 0; cf < 2; ++cf)
#pragma unroll
        for (int rf = 0; rf < 2; ++rf)
          acc[rf][cf] = __builtin_amdgcn_mfma_f32_32x32x16_bf16(
              ah[rf], wlr[sl][cf], acc[rf][cf], 0, 0, 0);
    }
    if (c + 1 < NC) {  // stage next chunk into the other LDS buffer
      const int nb = (c + 1) & 1;
      if (PACKED_IN) {
        destage(q0, q1, &AhS[nb][ss0], &AhS[nb][ss1]);
      } else {
        *(s16x8*)&AhS[nb][ss0] = cvt8(f0, f1);
        *(s16x8*)&AhS[nb][ss1] = cvt8(f2, f3);
      }
      __syncthreads();
    }
  }

  // ---- epilogue: acc[0] = t-even rows (b = m), acc[1] = t-odd (same b).
  // D layout col=lane&31, row m = (r&3)+8*(r>>2)+4*kg. Pack pairs to u32.
#pragma unroll
  for (int cf = 0; cf < 2; ++cf) {
    const int o = wave * 64 + cf * 32 + r31;
    const float bb = bias[o];
#pragma unroll
    for (int r = 0; r < 16; ++r) {
      const int mb = (r & 3) + 8 * (r >> 2) + 4 * kg;  // = b
      const float ze = acc[0][cf][r] + bb;
      const float zo = acc[1][cf][r] + bb;
      dstP[pbase + (size_t)mb * 512 + o] =
          (uint)f2bf(ze) | ((uint)f2bf(zo) << 16);
    }
  }
}

// ---------------------------------------------------------------------------
// IndRNN scan over packed z (u32 = bf16 z[2i] | bf16 z[2i+1]<<16), in-place:
// overwrites each u32 with packed bf16 s. Recurrence state kept in f32;
// stats (sum/sumsq) accumulated on the ROUNDED s (what the next GEMM reads).
// One thread per (b,h); CH=32 u32 chunks (64 t), register double-buffered.
// ---------------------------------------------------------------------------
__global__ __launch_bounds__(64) void indrnn_scan(uint* __restrict__ z,
                                                  const float* __restrict__ u,
                                                  float* __restrict__ stats) {
  const int gid = blockIdx.x * 64 + threadIdx.x;  // 0..16383
  const int h = gid & (H_DIM - 1);
  const float uu = u[h];
  float hh = 0.f, sum = 0.f, sumsq = 0.f;
  uint* p = z + gid;
  constexpr int STRIDE = B_DIM * H_DIM;  // 16384 u32
  constexpr int NI = T_DIM / 2;          // 1024 packed items per chain
  constexpr int CH = 32;
  constexpr int NCH = NI / CH;  // 32 chunks
  uint va[CH], vb[CH];

#define LOADC(dst, base)                                        \
  _Pragma("unroll") for (int c = 0; c < CH; ++c) dst[c] =       \
      p[(size_t)((base) + c) * STRIDE];
#define COMPC(dst)                                              \
  _Pragma("unroll") for (int c = 0; c < CH; ++c) {              \
    uint pk = dst[c];                                           \
    float ze = __uint_as_float(pk << 16);                       \
    float zo = __uint_as_float(pk & 0xffff0000u);               \
    hh = fmaxf(ze + uu * hh, 0.f);                              \
    unsigned short he = f2bf(hh);                               \
    float se = bf2f(he);                                        \
    sum += se; sumsq += se * se;                                \
    hh = fmaxf(zo + uu * hh, 0.f);                              \
    unsigned short ho = f2bf(hh);                               \
    float so = bf2f(ho);                                        \
    sum += so; sumsq += so * so;                                \
    dst[c] = (uint)he | ((uint)ho << 16);                       \
  }
#define STOREC(dst, base)                                       \
  _Pragma("unroll") for (int c = 0; c < CH; ++c)                \
      p[(size_t)((base) + c) * STRIDE] = dst[c];

  LOADC(va, 0)
  for (int i = 0; i < (NCH - 2) / 2; ++i) {
    const int t0 = i * 2 * CH;
    LOADC(vb, t0 + CH)
    COMPC(va)
    STOREC(va, t0)
    LOADC(va, t0 + 2 * CH)
    COMPC(vb)
    STOREC(vb, t0 + CH)
  }
  {
    const int t0 = (NCH - 2) * CH;
    LOADC(vb, t0 + CH)
    COMPC(va)
    STOREC(va, t0)
    COMPC(vb)
    STOREC(vb, t0 + CH)
  }
#undef LOADC
#undef COMPC
#undef STOREC
  atomicAdd(&stats[h], sum);
  atomicAdd(&stats[H_DIM + h], sumsq);
}

__global__ __launch_bounds__(64) void fill_sentinel(float* __restrict__ out,
                                                    int n) {
  for (int i = threadIdx.x; i < n; i += 64) out[i] = 1.0e6f;
}

// ---------------------------------------------------------------------------
// Convert raw f32 weights (layer 0) to bf16 hi/lo in fragment-swizzled order.
// ---------------------------------------------------------------------------
template <int K>
__global__ __launch_bounds__(256) void convert_w(
    const float* __restrict__ W, unsigned short* __restrict__ Whi,
    unsigned short* __restrict__ Wlo) {
  constexpr int NIT = K / 16;
  int i = blockIdx.x * 256 + threadIdx.x;
  if (i < H_DIM * K) {
    int o = i / K, k = i % K;
    float v = W[i];
    unsigned short h = f2bf(v);
    size_t idx =
        ((size_t)((o >> 5) * NIT + (k >> 4)) * 64 + ((k >> 3) & 1) * 32 +
         (o & 31)) * 8 + (k & 7);
    Whi[idx] = h;
    Wlo[idx] = f2bf(v - bf2f(h));
  }
}

// ---------------------------------------------------------------------------
// Fold BN of previous layer into next layer's weights, emit swizzled bf16:
//   a[i] = gamma[i]*rsqrt(var[i]+eps); c[i] = beta[i] - mean[i]*a[i]
//   Wf[o,i] = Wn[o,i]*a[i];  bf[o] = bn[o] + sum_i Wn[o,i]*c[i]
// ---------------------------------------------------------------------------
__global__ __launch_bounds__(256) void bn_fold(
    const float* __restrict__ stats, const float* __restrict__ gamma,
    const float* __restrict__ beta, const float* __restrict__ Wn,
    const float* __restrict__ bn, unsigned short* __restrict__ Whi,
    unsigned short* __restrict__ Wlo, float* __restrict__ bf) {
  constexpr int NIT = H_DIM / 16;
  const int o = blockIdx.x;
  const int tid = threadIdx.x;
  constexpr float invTB = 1.f / (float)(T_DIM * B_DIM);
  float part = 0.f;
  for (int i = tid; i < H_DIM; i += 256) {
    float mean = stats[i] * invTB;
    float var = stats[H_DIM + i] * invTB - mean * mean;
    float a = gamma[i] * rsqrtf(var + BN_EPS);
    float c = beta[i] - mean * a;
    float w = Wn[(size_t)o * H_DIM + i];
    float wf = w * a;
    unsigned short h = f2bf(wf);
    size_t idx =
        ((size_t)((o >> 5) * NIT + (i >> 4)) * 64 + ((i >> 3) & 1) * 32 +
         (o & 31)) * 8 + (i & 7);
    Whi[idx] = h;
    Wlo[idx] = f2bf(wf - bf2f(h));
    part += w * c;
  }
  __shared__ float red[256];
  red[tid] = part;
  __syncthreads();
  for (int s = 128; s > 0; s >>= 1) {
    if (tid < s) red[tid] += red[tid + s];
    __syncthreads();
  }
  if (tid == 0) bf[o] = bn[o] + red[0];
}

// ---------------------------------------------------------------------------
// Final: out[b,c] = sum_i (s5[T-1,b,i]*a5[i] + c5[i]) * Wout[c,i] + bout[c]
// s5 packed: t=2047 is the HIGH half of packed item i=1023.
// ---------------------------------------------------------------------------
__global__ __launch_bounds__(64) void final_out(const uint* __restrict__ s5,
                                                const float* __restrict__ stats,
                                                const float* __restrict__ gamma,
                                                const float* __restrict__ beta,
                                                const float* __restrict__ Wout,
                                                const float* __restrict__ bout,
                                                float* __restrict__ out) {
  const int b = blockIdx.x / C_DIM, cls = blockIdx.x % C_DIM;
  const int lane = threadIdx.x;
  constexpr float invTB = 1.f / (float)(T_DIM * B_DIM);
  const uint* srow =
      s5 + (size_t)(T_DIM / 2 - 1) * B_DIM * H_DIM + (size_t)b * H_DIM;
  float part = 0.f;
  for (int i = lane; i < H_DIM; i += 64) {
    float mean = stats[i] * invTB;
    float var = stats[H_DIM + i] * invTB - mean * mean;
    float a = gamma[i] * rsqrtf(var + BN_EPS);
    float c = beta[i] - mean * a;
    float sval = __uint_as_float(srow[i] & 0xffff0000u);
    part += (sval * a + c) * Wout[(size_t)cls * H_DIM + i];
  }
#pragma unroll
  for (int off = 32; off > 0; off >>= 1) part += __shfl_down(part, off);
  if (lane == 0) out[b * C_DIM + cls] = part + bout[cls];
}

// ---------------------------------------------------------------------------
extern "C" void kernel_launch(void* const* d_in, const int* in_sizes, int n_in,
                              void* d_out, int out_size, void* d_ws,
                              size_t ws_size, hipStream_t stream) {
  const float* x     = (const float*)d_in[0];
  const float* W0    = (const float*)d_in[1];
  const float* b0    = (const float*)d_in[2];
  const float* Wh    = (const float*)d_in[3];
  const float* bh    = (const float*)d_in[4];
  const float* u     = (const float*)d_in[5];
  const float* gamma = (const float*)d_in[6];
  const float* beta  = (const float*)d_in[7];
  const float* Wout  = (const float*)d_in[8];
  const float* bout  = (const float*)d_in[9];
  float* out = (float*)d_out;

  const size_t need = PKN * sizeof(uint) +
                      (size_t)H_DIM * H_DIM * 2 * sizeof(unsigned short) +
                      3 * H_DIM * sizeof(float);
  if (ws_size < need) {
    fill_sentinel<<<1, 64, 0, stream>>>(out, out_size);
    return;
  }

  uint* buf = (uint*)d_ws;                             // 64 MB packed acts
  unsigned short* Whi = (unsigned short*)(buf + PKN);  // 512 KB
  unsigned short* Wlo = Whi + (size_t)H_DIM * H_DIM;   // 512 KB
  float* bf = (float*)(Wlo + (size_t)H_DIM * H_DIM);   // 2 KB
  float* stats = bf + H_DIM;                           // 4 KB

  const int gemm_blocks = TB / ROWS;  // 1024
  const int scan_blocks = (B_DIM * H_DIM) / 64;

  // ---- layer 0: x (f32, K=128) -> buf (packed) ----
  convert_w<D_DIM><<<(H_DIM * D_DIM + 255) / 256, 256, 0, stream>>>(W0, Whi,
                                                                    Wlo);
  gemm_mfma<D_DIM, false><<<gemm_blocks, 512, 0, stream>>>(x, Whi, Wlo, b0,
                                                           buf, stats);
  indrnn_scan<<<scan_blocks, 64, 0, stream>>>(buf, u, stats);

  // ---- layers 1..5: fully in-place on the 64 MB packed buffer ----
  for (int l = 1; l < L_DIM; ++l) {
    bn_fold<<<H_DIM, 256, 0, stream>>>(
        stats, gamma + (size_t)(l - 1) * H_DIM, beta + (size_t)(l - 1) * H_DIM,
        Wh + (size_t)(l - 1) * H_DIM * H_DIM, bh + (size_t)(l - 1) * H_DIM,
        Whi, Wlo, bf);
    gemm_mfma<H_DIM, true><<<gemm_blocks, 512, 0, stream>>>(buf, Whi, Wlo, bf,
                                                            buf, stats);
    indrnn_scan<<<scan_blocks, 64, 0, stream>>>(buf, u + (size_t)l * H_DIM,
                                                stats);
  }

  // ---- final projection (BN of layer 5 applied on the fly) ----
  final_out<<<B_DIM * C_DIM, 64, 0, stream>>>(
      buf, stats, gamma + 5 * (size_t)H_DIM, beta + 5 * (size_t)H_DIM, Wout,
      bout, out);
}